// Round 2
// baseline (21.067 us; speedup 1.0000x reference)
//
#include <hip/hip_runtime.h>
#include <hip/hip_bf16.h>

// out[n] = exp(-0.5 * (x[n]-mu)^T cov (x[n]-mu)), x:[N,2] f32, mu:[2], cov:[2,2]
// Streaming, memory-bound. Exact-fit grid (no grid-stride loop) + nontemporal
// loads/stores (no reuse -> don't pollute L2).

typedef float f32x4 __attribute__((ext_vector_type(4)));

__global__ __launch_bounds__(256) void gauss_pdf_kernel(
    const f32x4* __restrict__ x4,
    const float* __restrict__ mu,
    const float* __restrict__ cov,
    f32x4* __restrict__ out4,
    int n4) {
    // Wave-uniform scalar loads (s_load), negligible traffic.
    const float mx  = mu[0];
    const float my  = mu[1];
    const float c00 = cov[0];
    const float cxy = cov[1] + cov[2];
    const float c11 = cov[3];

    int i = blockIdx.x * blockDim.x + threadIdx.x;
    if (i >= n4) return;

    // 4 points per thread: 32B contiguous load, 16B store.
    f32x4 a = __builtin_nontemporal_load(&x4[2 * i]);
    f32x4 b = __builtin_nontemporal_load(&x4[2 * i + 1]);

    f32x4 r;
    float dx = a.x - mx, dy = a.y - my;
    r.x = __expf(-0.5f * (c00 * dx * dx + cxy * dx * dy + c11 * dy * dy));

    dx = a.z - mx; dy = a.w - my;
    r.y = __expf(-0.5f * (c00 * dx * dx + cxy * dx * dy + c11 * dy * dy));

    dx = b.x - mx; dy = b.y - my;
    r.z = __expf(-0.5f * (c00 * dx * dx + cxy * dx * dy + c11 * dy * dy));

    dx = b.z - mx; dy = b.w - my;
    r.w = __expf(-0.5f * (c00 * dx * dx + cxy * dx * dy + c11 * dy * dy));

    __builtin_nontemporal_store(r, &out4[i]);
}

// Scalar tail for N % 4 != 0 (not hit at N=8388608, kept for correctness).
__global__ void gauss_pdf_tail(const float* __restrict__ x,
                               const float* __restrict__ mu,
                               const float* __restrict__ cov,
                               float* __restrict__ out,
                               int start, int n) {
    const float mx  = mu[0];
    const float my  = mu[1];
    const float c00 = cov[0];
    const float cxy = cov[1] + cov[2];
    const float c11 = cov[3];
    for (int i = start + threadIdx.x; i < n; i += blockDim.x) {
        float dx = x[2 * i] - mx, dy = x[2 * i + 1] - my;
        out[i] = __expf(-0.5f * (c00 * dx * dx + cxy * dx * dy + c11 * dy * dy));
    }
}

extern "C" void kernel_launch(void* const* d_in, const int* in_sizes, int n_in,
                              void* d_out, int out_size, void* d_ws, size_t ws_size,
                              hipStream_t stream) {
    const float* x   = (const float*)d_in[0];   // [N,2]
    const float* mu  = (const float*)d_in[1];   // [2]
    const float* cov = (const float*)d_in[2];   // [2,2]
    float* out       = (float*)d_out;           // [N]

    const int n  = out_size;   // N points
    const int n4 = n / 4;

    const int block = 256;
    const int grid  = (n4 + block - 1) / block;   // exact fit, no loop

    if (n4 > 0) {
        gauss_pdf_kernel<<<grid, block, 0, stream>>>(
            (const f32x4*)x, mu, cov, (f32x4*)out, n4);
    }

    int rem = n - n4 * 4;
    if (rem > 0) {
        gauss_pdf_tail<<<1, 64, 0, stream>>>(x, mu, cov, out, n4 * 4, n);
    }
}